// Round 8
// baseline (50.048 us; speedup 1.0000x reference)
//
#include <hip/hip_runtime.h>
#include <math.h>

// GCDD fused v8: zero-LDS register-pipeline sweep + 1-iter load prefetch.
// out = u + div( phi(G)*ux, phi(G)*uy ); 3x3 Sobel cross-correlations with zero
// padding at EVERY conv stage (intermediates forced to 0 outside the domain).
//
// R7 post-mortem: VALU-issue-bound, 60% busy / 40% stall. The stall: u row T
// was loaded and consumed in the SAME iteration (load->use distance ~0), so
// every iter waits out L2/L3 latency. R8: iter T loads band-row T+1 (uw depth
// 4), giving a full iteration (~1000 cyc) of independent compute between load
// and use. Rotation period lcm(4,3)=12 -> 12x-unrolled loop, all slot indices
// literal (runtime-indexed arrays would go to scratch). Output stores are
// nontemporal (pure streaming; keep u resident in L2/L3).
//
// Pipeline at iter T (band-row k <-> abs gy = gy0 + k - 3):
//   L'(T): load u band-row T+1 -> uw[(T+1)%4]      (abs gy0+T-2)
//   UX(T): ux/uy band-row T-1  -> xw/yw[(T-1)%3]   (abs gy0+T-4)
//   PQ(T): P,Q  band-row T-2   -> dP/eQ[(T-2)%3]   (abs gy0+T-5), pre-reduced:
//          dP=P[c+1]-P[c-1], eQ=Q[c-1]+2Q[c]+Q[c+1]
//   OUT(T): out band-row T-3 = u + (dP[r-1]+2dP[r]+dP[r+1]) + (eQ[r+1]-eQ[r-1])
// Block: 256 threads = 2 bands x 128 strips (4 cols each). Grid y = H/(2*HB).

#define HB   16
#define NROW (HB + 6)   // 22 active pipeline iterations (loop padded to 24)
#define NT   256

typedef float f4v __attribute__((ext_vector_type(4)));

// Args: TT iter; LS = (TT+1)%4 load/residual slot; AT/AM/AB = uw slots of rows
// TT-2/TT-1/TT; XW = xw write slot ((TT-1)%3); XT/XM/XB = xw slots of ux rows
// TT-3/TT-2/TT-1; PW = dP write slot ((TT-2)%3); PT/PM/PB = dP slots of P rows
// TT-4/TT-3/TT-2 (out-row r-1, r, r+1).
#define STEP(TT, LS, AT, AM, AB, XW, XT, XM, XB, PW, PT, PM, PB) do {          \
    const int Tt = (TT);                                                       \
    /* residual u for OUT (band-row Tt-3, slot LS) BEFORE L' overwrites it */  \
    const float ur0 = ucen[LS][0], ur1 = ucen[LS][1],                          \
                ur2 = ucen[LS][2], ur3 = ucen[LS][3];                          \
    if (Tt + 1 < NROW) {                                                       \
        /* ---- L'(Tt): u band-row Tt+1, abs gy = gy0+Tt-2 ---- */             \
        const int gy = gy0 + Tt - 2;                                           \
        float* w = uw[LS];                                                     \
        if ((unsigned)gy < (unsigned)H) {                                      \
            const float* row = uc + (long)gy * W;                              \
            const float4 va = *(const float4*)(row + ca);                      \
            const float4 vb = *(const float4*)(row + c0);                      \
            const float4 vc = *(const float4*)(row + cc);                      \
            w[0] = inb0  ? va.x : 0.f;  w[1]  = inb1  ? va.y : 0.f;            \
            w[2] = inb2  ? va.z : 0.f;  w[3]  = inb3  ? va.w : 0.f;            \
            w[4] = vb.x;                w[5]  = vb.y;                          \
            w[6] = vb.z;                w[7]  = vb.w;                          \
            w[8] = inb8  ? vc.x : 0.f;  w[9]  = inb9  ? vc.y : 0.f;            \
            w[10] = inb10 ? vc.z : 0.f; w[11] = inb11 ? vc.w : 0.f;            \
        } else {                                                               \
            _Pragma("unroll") for (int i = 0; i < 12; ++i) w[i] = 0.f;         \
        }                                                                      \
        ucen[LS][0] = w[4]; ucen[LS][1] = w[5];                                \
        ucen[LS][2] = w[6]; ucen[LS][3] = w[7];                                \
    }                                                                          \
    if (Tt >= 2 && Tt < NROW) {                                                \
        /* ---- UX(Tt): ux/uy band-row Tt-1, abs gy = gy0+Tt-4 ---- */         \
        float* xr = xw[XW]; float* yr = yw[XW];                                \
        const int gy = gy0 + Tt - 4;                                           \
        if ((unsigned)gy < (unsigned)H) {                                      \
            const float* a = uw[AT];   /* row Tt-2 */                          \
            const float* m = uw[AM];   /* row Tt-1 */                          \
            const float* b = uw[AB];   /* row Tt   */                          \
            _Pragma("unroll") for (int c = 0; c < 8; ++c) {                    \
                const float A = a[c+1], B = a[c+2], C = a[c+3];                \
                const float D = m[c+1],             E = m[c+3];                \
                const float F = b[c+1], Gg = b[c+2], Hh = b[c+3];              \
                const float x = (C - A) + 2.f*(E - D) + (Hh - F);              \
                const float y = (F + 2.f*Gg + Hh) - (A + 2.f*B + C);           \
                xr[c] = mU[c+2] ? x : 0.f;                                     \
                yr[c] = mU[c+2] ? y : 0.f;                                     \
            }                                                                  \
        } else {                                                               \
            _Pragma("unroll") for (int c = 0; c < 8; ++c) { xr[c]=0.f; yr[c]=0.f; } \
        }                                                                      \
    }                                                                          \
    if (Tt >= 4 && Tt < NROW) {                                                \
        /* ---- PQ(Tt): P band-row Tt-2, abs gy = gy0+Tt-5 ---- */             \
        float* dp = dP[PW]; float* eq = eQ[PW];                                \
        const int gy = gy0 + Tt - 5;                                           \
        if ((unsigned)gy < (unsigned)H) {                                      \
            const float* xt = xw[XT];  /* ux row Tt-3 */                       \
            const float* xm = xw[XM];  /* ux row Tt-2 */                       \
            const float* xb = xw[XB];  /* ux row Tt-1 */                       \
            const float* yt = yw[XT];                                          \
            const float* ym = yw[XM];                                          \
            const float* yb = yw[XB];                                          \
            float P[6], Q[6];                                                  \
            _Pragma("unroll") for (int c = 0; c < 6; ++c) {                    \
                const float xc = xm[c+1], yc = ym[c+1];                        \
                const float uxx = (xt[c+2]-xt[c]) + 2.f*(xm[c+2]-xm[c])        \
                                + (xb[c+2]-xb[c]);                             \
                const float uxy = (xb[c] + 2.f*xb[c+1] + xb[c+2])              \
                                - (xt[c] + 2.f*xt[c+1] + xt[c+2]);             \
                const float uyy = (yb[c] + 2.f*yb[c+1] + yb[c+2])              \
                                - (yt[c] + 2.f*yt[c+1] + yt[c+2]);             \
                const float den = 1.f + xc*xc + yc*yc;                         \
                const float Gv = (uxx*uyy - uxy*uxy)                           \
                               * __builtin_amdgcn_rcpf(den*den + 1e-6f);       \
                const float phi = __expf(-fabsf(Gv));                          \
                P[c] = mU[c+3] ? phi * xc : 0.f;                               \
                Q[c] = mU[c+3] ? phi * yc : 0.f;                               \
            }                                                                  \
            dp[0] = P[2]-P[0]; dp[1] = P[3]-P[1];                              \
            dp[2] = P[4]-P[2]; dp[3] = P[5]-P[3];                              \
            eq[0] = Q[0]+2.f*Q[1]+Q[2]; eq[1] = Q[1]+2.f*Q[2]+Q[3];            \
            eq[2] = Q[2]+2.f*Q[3]+Q[4]; eq[3] = Q[3]+2.f*Q[4]+Q[5];            \
        } else {                                                               \
            _Pragma("unroll") for (int c = 0; c < 4; ++c) { dp[c]=0.f; eq[c]=0.f; } \
        }                                                                      \
    }                                                                          \
    if (Tt >= 6 && Tt < NROW) {                                                \
        /* ---- OUT(Tt): out band-row Tt-3, abs gy = gy0+Tt-6 (in-domain) ---- */ \
        f4v o;                                                                 \
        o.x = ur0 + (dP[PT][0] + 2.f*dP[PM][0] + dP[PB][0])                    \
                  + (eQ[PB][0] - eQ[PT][0]);                                   \
        o.y = ur1 + (dP[PT][1] + 2.f*dP[PM][1] + dP[PB][1])                    \
                  + (eQ[PB][1] - eQ[PT][1]);                                   \
        o.z = ur2 + (dP[PT][2] + 2.f*dP[PM][2] + dP[PB][2])                    \
                  + (eQ[PB][2] - eQ[PT][2]);                                   \
        o.w = ur3 + (dP[PT][3] + 2.f*dP[PM][3] + dP[PB][3])                    \
                  + (eQ[PB][3] - eQ[PT][3]);                                   \
        __builtin_nontemporal_store(o, (f4v*)(oc + (long)(gy0 + Tt - 6) * W + c0)); \
    }                                                                          \
} while (0)

__global__ __launch_bounds__(NT) void gcdd_sweep(
    const float* __restrict__ u, float* __restrict__ out, int H, int W)
{
    const int tid   = threadIdx.x;
    const int strip = tid & 127;          // 128 strips x 4 cols = W = 512
    const int band  = tid >> 7;           // 2 bands per block (wave-uniform)
    const int c0    = strip * 4;
    const int gy0   = (blockIdx.y * 2 + band) * HB;
    const long chan = blockIdx.z;
    const float* __restrict__ uc = u + chan * (long)H * W;
    float* __restrict__ oc = out + chan * (long)H * W;

    // Clamped load-base cols (keeps addresses in-bounds; clamped-in values are
    // masked to zero below, implementing the zero-padding of the first conv).
    const int ca = (c0 - 4 < 0) ? 0 : (c0 - 4);
    const int cc = (c0 + 4 > W - 4) ? (W - 4) : (c0 + 4);

    // uw[i] holds u col c0-4+i; validity masks (only edge strips have false).
    bool mU[12];
    #pragma unroll
    for (int i = 0; i < 12; ++i)
        mU[i] = (unsigned)(c0 - 4 + i) < (unsigned)W;
    const bool inb0 = mU[0], inb1 = mU[1], inb2 = mU[2], inb3 = mU[3];
    const bool inb8 = mU[8], inb9 = mU[9], inb10 = mU[10], inb11 = mU[11];

    float uw[4][12];
    float ucen[4][4] = {};
    float xw[3][8], yw[3][8];
    float dP[3][4], eQ[3][4];

    // ---- Prologue: load band-row 0 (abs gy = gy0-3) into slot 0 ----
    {
        const int gy = gy0 - 3;
        float* w = uw[0];
        if ((unsigned)gy < (unsigned)H) {
            const float* row = uc + (long)gy * W;
            const float4 va = *(const float4*)(row + ca);
            const float4 vb = *(const float4*)(row + c0);
            const float4 vc = *(const float4*)(row + cc);
            w[0] = inb0  ? va.x : 0.f;  w[1]  = inb1  ? va.y : 0.f;
            w[2] = inb2  ? va.z : 0.f;  w[3]  = inb3  ? va.w : 0.f;
            w[4] = vb.x;                w[5]  = vb.y;
            w[6] = vb.z;                w[7]  = vb.w;
            w[8] = inb8  ? vc.x : 0.f;  w[9]  = inb9  ? vc.y : 0.f;
            w[10] = inb10 ? vc.z : 0.f; w[11] = inb11 ? vc.w : 0.f;
        } else {
            #pragma unroll
            for (int i = 0; i < 12; ++i) w[i] = 0.f;
        }
        ucen[0][0] = w[4]; ucen[0][1] = w[5];
        ucen[0][2] = w[6]; ucen[0][3] = w[7];
    }

    // 24 iterations (22 active), 12x-unrolled: uw rotates mod 4, xw/dP mod 3.
    for (int t = 0; t < 24; t += 12) {
        STEP(t + 0,  1, 2, 3, 0,  2, 0, 1, 2,  1, 2, 0, 1);
        STEP(t + 1,  2, 3, 0, 1,  0, 1, 2, 0,  2, 0, 1, 2);
        STEP(t + 2,  3, 0, 1, 2,  1, 2, 0, 1,  0, 1, 2, 0);
        STEP(t + 3,  0, 1, 2, 3,  2, 0, 1, 2,  1, 2, 0, 1);
        STEP(t + 4,  1, 2, 3, 0,  0, 1, 2, 0,  2, 0, 1, 2);
        STEP(t + 5,  2, 3, 0, 1,  1, 2, 0, 1,  0, 1, 2, 0);
        STEP(t + 6,  3, 0, 1, 2,  2, 0, 1, 2,  1, 2, 0, 1);
        STEP(t + 7,  0, 1, 2, 3,  0, 1, 2, 0,  2, 0, 1, 2);
        STEP(t + 8,  1, 2, 3, 0,  1, 2, 0, 1,  0, 1, 2, 0);
        STEP(t + 9,  2, 3, 0, 1,  2, 0, 1, 2,  1, 2, 0, 1);
        STEP(t + 10, 3, 0, 1, 2,  0, 1, 2, 0,  2, 0, 1, 2);
        STEP(t + 11, 0, 1, 2, 3,  1, 2, 0, 1,  0, 1, 2, 0);
    }
}

extern "C" void kernel_launch(void* const* d_in, const int* in_sizes, int n_in,
                              void* d_out, int out_size, void* d_ws, size_t ws_size,
                              hipStream_t stream) {
    const float* u = (const float*)d_in[0];
    float* out = (float*)d_out;

    const int H = 512, W = 512;
    const int channels = in_sizes[0] / (H * W);  // B*C = 48

    dim3 grid(1, H / (2 * HB), channels);        // 1 x 16 x 48 = 768 blocks
    dim3 block(NT);
    gcdd_sweep<<<grid, block, 0, stream>>>(u, out, H, W);
}